// Round 7
// baseline (2967.248 us; speedup 1.0000x reference)
//
#include <hip/hip_runtime.h>
#include <math.h>

#define HH 512
#define LL 128
#define BB 4
#define TT 130            // L + 2
#define G4 2048           // 4*H

typedef float f32x4_ __attribute__((ext_vector_type(4)));
typedef int   i32x2_ __attribute__((ext_vector_type(2)));

// ---- ws layout (float indices) ----
// HF: 131 slots of [B][H] = 131*2048 floats   (history, for K3; plain stores)
// HB: same
// Hx: tagged exchange ring: int2[2 dir][4 ring][32 rec][64 lane] = 131072 B
#define HF_OFF 0
#define HB_OFF 268288
#define HX_OFF 536576
// xproj lives in the TAIL of d_out (K3 overwrites it last): 2 * 130*4*2048 floats
#define XPROJ_PER_DIR (TT * BB * G4)              // 1064960
#define XPROJ_OFF (67108864 - 2 * XPROJ_PER_DIR)  // 64978944

// ---------------- K1: input projection GEMM (both dirs) ----------------
__global__ __launch_bounds__(256) void k1_xproj(
    const float* __restrict__ wr,
    const float* __restrict__ WihF, const float* __restrict__ bF,
    const float* __restrict__ WihB, const float* __restrict__ bB,
    float* __restrict__ outbuf) {
    __shared__ float As[16][132];
    __shared__ float Bs[16][132];
    int bid = blockIdx.x;
    int d = bid / 80;
    int r2 = bid % 80;
    int mt = r2 >> 4, nt = r2 & 15;
    const float* Wih  = d ? WihB : WihF;
    const float* bias = d ? bB : bF;
    float* xp = outbuf + XPROJ_OFF + (size_t)d * XPROJ_PER_DIR;
    int tid = threadIdx.x;
    int ty = tid >> 4, tx = tid & 15;
    int m0 = mt * 128, n0 = nt * 128;

    float acc[8][8];
#pragma unroll
    for (int i = 0; i < 8; i++)
#pragma unroll
        for (int j = 0; j < 8; j++) acc[i][j] = 0.f;

    for (int k0 = 0; k0 < HH; k0 += 16) {
#pragma unroll
        for (int l = tid; l < 512; l += 256) {
            int rrow = l & 127;
            int kq = l >> 7;
            int m = m0 + rrow;
            int t = m >> 2, b = m & 3;
            float4 av = make_float4(0.f, 0.f, 0.f, 0.f);
            if (t >= 1 && t <= 128)
                av = *(const float4*)&wr[((size_t)b * LL + (t - 1)) * HH + k0 + kq * 4];
            As[kq * 4 + 0][rrow] = av.x;
            As[kq * 4 + 1][rrow] = av.y;
            As[kq * 4 + 2][rrow] = av.z;
            As[kq * 4 + 3][rrow] = av.w;
            float4 bv = *(const float4*)&Wih[(size_t)(n0 + rrow) * HH + k0 + kq * 4];
            Bs[kq * 4 + 0][rrow] = bv.x;
            Bs[kq * 4 + 1][rrow] = bv.y;
            Bs[kq * 4 + 2][rrow] = bv.z;
            Bs[kq * 4 + 3][rrow] = bv.w;
        }
        __syncthreads();
#pragma unroll
        for (int kk = 0; kk < 16; kk++) {
            float4 a0 = *(const float4*)&As[kk][ty * 8];
            float4 a1 = *(const float4*)&As[kk][ty * 8 + 4];
            float4 b0 = *(const float4*)&Bs[kk][tx * 8];
            float4 b1 = *(const float4*)&Bs[kk][tx * 8 + 4];
            float am[8] = {a0.x, a0.y, a0.z, a0.w, a1.x, a1.y, a1.z, a1.w};
            float bn[8] = {b0.x, b0.y, b0.z, b0.w, b1.x, b1.y, b1.z, b1.w};
#pragma unroll
            for (int i = 0; i < 8; i++)
#pragma unroll
                for (int j = 0; j < 8; j++) acc[i][j] = fmaf(am[i], bn[j], acc[i][j]);
        }
        __syncthreads();
    }
    float4 bv0 = *(const float4*)&bias[n0 + tx * 8];
    float4 bv1 = *(const float4*)&bias[n0 + tx * 8 + 4];
#pragma unroll
    for (int i = 0; i < 8; i++) {
        int m = m0 + ty * 8 + i;
        if (m < TT * BB) {
            float4 o0 = make_float4(acc[i][0] + bv0.x, acc[i][1] + bv0.y,
                                    acc[i][2] + bv0.z, acc[i][3] + bv0.w);
            float4 o1 = make_float4(acc[i][4] + bv1.x, acc[i][5] + bv1.y,
                                    acc[i][6] + bv1.z, acc[i][7] + bv1.w);
            *(float4*)&xp[(size_t)m * G4 + n0 + tx * 8] = o0;
            *(float4*)&xp[(size_t)m * G4 + n0 + tx * 8 + 4] = o1;
        }
    }
}

__device__ __forceinline__ float sigm_(float x) { return 1.f / (1.f + __expf(-x)); }
__device__ __forceinline__ float tanh_(float x) {
    float xc = fminf(fmaxf(x, -15.f), 15.f);
    float e = __expf(-2.f * xc);
    return (1.f - e) / (1.f + e);
}

// ---------------- K2: persistent bidirectional LSTM recurrence ----------------
// 64 blocks: 0..31 fwd, 32..63 bwd. Block g owns 16 hidden units (64 W_hh rows,
// register-resident). Exchange: tagged write-once 8-B atoms (data-is-the-flag).
// R6 lesson: hop count is NOT the cost — continuous polling by 256 waves
// starves producer stores at the coherence point. Fix: ONE polling wave per
// block + s_sleep backoff; other waves park at s_barrier (zero traffic).
__global__ __launch_bounds__(256, 1) void k2_lstm(
    const float* __restrict__ WhhF, const float* __restrict__ WhhB,
    const float* __restrict__ outbuf, float* __restrict__ ws) {
    __shared__ __align__(16) float hlds_f[2048];   // h staged, XOR-swizzled f4 layout
    __shared__ float g_lds[64][4];
    __shared__ float clds[16][4];

    int bid = blockIdx.x;
    int dir = bid >> 5;
    int g = bid & 31;
    int j0 = g * 16;
    const float* Whh = dir ? WhhB : WhhF;
    const float* xp = outbuf + XPROJ_OFF + (size_t)dir * XPROJ_PER_DIR;
    float* Hbase = ws + (dir ? HB_OFF : HF_OFF);
    i32x2_* Hx = (i32x2_*)(ws + HX_OFF);
    int tid = threadIdx.x;
    int rg = tid >> 5, cc = tid & 31;  // 8 row-groups x 32 col-chunks
    int lane = tid & 63;

    // ---- weights: thread owns 8 rows x 16 cols of the block's 64x512 slice
    float w[8][16];
#pragma unroll
    for (int i = 0; i < 8; i++) {
        int rl = rg * 8 + i;
        int q = rl >> 4, u = rl & 15;
        const float* wrow = Whh + (size_t)(q * 512 + j0 + u) * HH + cc * 16;
#pragma unroll
        for (int c4 = 0; c4 < 4; c4++) {
            float4 vv = *(const float4*)&wrow[c4 * 4];
            w[i][c4 * 4 + 0] = vv.x;
            w[i][c4 * 4 + 1] = vv.y;
            w[i][c4 * 4 + 2] = vv.z;
            w[i][c4 * 4 + 3] = vv.w;
        }
    }

    int u_ = (tid >> 2) & 15, b_ = tid & 3;  // gate-thread mapping (tid<64)
    int su = lane >> 2, sb = lane & 3;       // scatter mapping (poll wave)

    for (int s = 0; s < TT; s++) {
        int t = dir ? (129 - s) : s;
        int slot_in = dir ? (t + 1) : t;
        int slot_out = dir ? t : (t + 1);

        // ---- poll+scatter: WAVE 0 ONLY. Staged 32-record sweep, sleep backoff.
        if (s > 0 && tid < 64) {
            const char* rb = (const char*)(Hx +
                (size_t)(dir * 4 + (slot_in & 3)) * 32 * 64) + lane * 8;
            unsigned rdy = 0;
#define PL(D, B, O) asm volatile(                                          \
    "global_load_dwordx2 %0, %1, off offset:" O " sc0 sc1"                 \
    : "=v"(D) : "v"(B) : "memory")
#define CHK(D, R) if (!((rdy >> (R)) & 1u) && __all((D).y == slot_in)) {   \
        int quad = (R) * 4 + (su >> 2);                                    \
        int qs = quad ^ ((quad >> 2) & 7);                                 \
        hlds_f[(sb * 128 + qs) * 4 + (su & 3)] = __int_as_float((D).x);    \
        rdy |= (1u << (R)); }
            while (rdy != 0xFFFFFFFFu) {
                i32x2_ d00, d01, d02, d03, d04, d05, d06, d07;
                i32x2_ d10, d11, d12, d13, d14, d15, d16, d17;
                i32x2_ d20, d21, d22, d23, d24, d25, d26, d27;
                i32x2_ d30, d31, d32, d33, d34, d35, d36, d37;
                const char* b0 = rb;
                const char* b1 = rb + 4096;
                const char* b2 = rb + 8192;
                const char* b3 = rb + 12288;
                PL(d00, b0, "0");    PL(d01, b0, "512");  PL(d02, b0, "1024");
                PL(d03, b0, "1536"); PL(d04, b0, "2048"); PL(d05, b0, "2560");
                PL(d06, b0, "3072"); PL(d07, b0, "3584");
                PL(d10, b1, "0");    PL(d11, b1, "512");  PL(d12, b1, "1024");
                PL(d13, b1, "1536"); PL(d14, b1, "2048"); PL(d15, b1, "2560");
                PL(d16, b1, "3072"); PL(d17, b1, "3584");
                asm volatile("s_waitcnt vmcnt(8)" ::: "memory");
                CHK(d00, 0) CHK(d01, 1) CHK(d02, 2) CHK(d03, 3)
                CHK(d04, 4) CHK(d05, 5) CHK(d06, 6) CHK(d07, 7)
                PL(d20, b2, "0");    PL(d21, b2, "512");  PL(d22, b2, "1024");
                PL(d23, b2, "1536"); PL(d24, b2, "2048"); PL(d25, b2, "2560");
                PL(d26, b2, "3072"); PL(d27, b2, "3584");
                asm volatile("s_waitcnt vmcnt(8)" ::: "memory");
                CHK(d10, 8)  CHK(d11, 9)  CHK(d12, 10) CHK(d13, 11)
                CHK(d14, 12) CHK(d15, 13) CHK(d16, 14) CHK(d17, 15)
                PL(d30, b3, "0");    PL(d31, b3, "512");  PL(d32, b3, "1024");
                PL(d33, b3, "1536"); PL(d34, b3, "2048"); PL(d35, b3, "2560");
                PL(d36, b3, "3072"); PL(d37, b3, "3584");
                asm volatile("s_waitcnt vmcnt(8)" ::: "memory");
                CHK(d20, 16) CHK(d21, 17) CHK(d22, 18) CHK(d23, 19)
                CHK(d24, 20) CHK(d25, 21) CHK(d26, 22) CHK(d27, 23)
                asm volatile("s_waitcnt vmcnt(0)" ::: "memory");
                CHK(d30, 24) CHK(d31, 25) CHK(d32, 26) CHK(d33, 27)
                CHK(d34, 28) CHK(d35, 29) CHK(d36, 30) CHK(d37, 31)
                if (rdy != 0xFFFFFFFFu) asm volatile("s_sleep 2");
            }
#undef PL
#undef CHK
        }
        __syncthreads();  // A: h staged (waves 1-3 were parked here, silent)

        // xq prefetch for THIS step's gates: issue now, hidden under dot
        float xq[4] = {0.f, 0.f, 0.f, 0.f};
        if (tid < 64) {
#pragma unroll
            for (int q = 0; q < 4; q++)
                xq[q] = xp[((size_t)t * BB + b_) * G4 + q * 512 + j0 + u_];
        }

        float vred = 0.f;
        if (s > 0) {
            // ---- dot: v[i*4+b] partial over this thread's 16 cols (all waves)
            float v[32];
#pragma unroll
            for (int i = 0; i < 32; i++) v[i] = 0.f;
            const f32x4_* hlds4 = (const f32x4_*)hlds_f;
#pragma unroll
            for (int b = 0; b < 4; b++) {
#pragma unroll
                for (int c4 = 0; c4 < 4; c4++) {
                    int quad = cc * 4 + c4;
                    int qs = quad ^ (cc & 7);
                    f32x4_ h4 = hlds4[b * 128 + qs];
#pragma unroll
                    for (int i = 0; i < 8; i++) {
                        float* pv = &v[i * 4 + b];
                        *pv = fmaf(w[i][c4 * 4 + 0], h4.x, *pv);
                        *pv = fmaf(w[i][c4 * 4 + 1], h4.y, *pv);
                        *pv = fmaf(w[i][c4 * 4 + 2], h4.z, *pv);
                        *pv = fmaf(w[i][c4 * 4 + 3], h4.w, *pv);
                    }
                }
            }
            // ---- halving reduce over 32 lanes: lane cc ends with value idx cc
            int n = 16;
#pragma unroll
            for (int m = 16; m >= 1; m >>= 1) {
                bool up = (cc & m) != 0;
#pragma unroll
                for (int j = 0; j < 16; j++) {
                    if (j < n) {
                        float send = up ? v[j] : v[j + n];
                        float recv = __shfl_xor(send, m, 64);
                        v[j] = (up ? v[j + n] : v[j]) + recv;
                    }
                }
                n >>= 1;
            }
            vred = v[0];
        }
        // lane cc of rg holds gate value (row rg*8 + (cc>>2), batch cc&3)
        g_lds[rg * 8 + (cc >> 2)][cc & 3] = vred;
        __syncthreads();  // B

        // ---- gates + state update + publish (wave 0: 16 units x 4 batches)
        if (tid < 64) {
            float gv[4];
#pragma unroll
            for (int q = 0; q < 4; q++) gv[q] = g_lds[q * 16 + u_][b_] + xq[q];
            float cprev = (s == 0) ? 0.f : clds[u_][b_];
            float si = sigm_(gv[0]);
            float sf = sigm_(gv[1]);
            float tg = tanh_(gv[2]);
            float so = sigm_(gv[3]);
            float cn = sf * cprev + si * tg;
            clds[u_][b_] = cn;
            float hval = so * tanh_(cn);
            // tagged publish FIRST (critical path): write-once atom = its own flag
            i32x2_ pub;
            pub.x = __float_as_int(hval);
            pub.y = slot_out;
            i32x2_* pp = Hx + ((size_t)(dir * 4 + (slot_out & 3)) * 32 + g) * 64 + tid;
            asm volatile("global_store_dwordx2 %0, %1, off sc0 sc1"
                         :: "v"(pp), "v"(pub) : "memory");
            // history for K3 (plain cached store; kernel boundary publishes it)
            Hbase[(size_t)slot_out * G4 + b_ * HH + j0 + u_] = hval;
        }
        // no waitcnt, no flag, no trailing barrier
    }
}

// ---------------- K3: pairwise span diffs -> output ----------------
__global__ __launch_bounds__(256) void k3_out(const float* __restrict__ ws,
                                              float* __restrict__ out) {
    const float* HF = ws + HF_OFF;
    const float* HB = ws + HB_OFF;
    size_t idx = (size_t)blockIdx.x * 256 + threadIdx.x;
    const size_t total = 16777216;  // f4 count
    const size_t stride = (size_t)2048 * 256;
    for (; idx < total; idx += stride) {
        int c4 = idx & 255;
        int b = (idx >> 8) & 3;
        int k = (idx >> 10) & 127;
        int i = (int)(idx >> 17);
        f32x4_ res = (f32x4_)0.f;
        if (i >= 1 && k > i && k <= 126) {
            int c0 = c4 * 4;
            if (c0 < 512) {
                const f32x4_ a = *(const f32x4_*)&HF[(size_t)(k + 1) * G4 + b * HH + c0];
                const f32x4_ c = *(const f32x4_*)&HF[(size_t)(i + 1) * G4 + b * HH + c0];
                res = a - c;
            } else {
                int cd = c0 - 512;
                const f32x4_ a = *(const f32x4_*)&HB[(size_t)(i + 1) * G4 + b * HH + cd];
                const f32x4_ c = *(const f32x4_*)&HB[(size_t)(k + 1) * G4 + b * HH + cd];
                res = a - c;
            }
        }
        __builtin_nontemporal_store(res, (f32x4_*)&out[idx * 4]);
    }
}

extern "C" void kernel_launch(void* const* d_in, const int* in_sizes, int n_in,
                              void* d_out, int out_size, void* d_ws, size_t ws_size,
                              hipStream_t stream) {
    const float* wr   = (const float*)d_in[0];
    const float* WihF = (const float*)d_in[1];
    const float* WhhF = (const float*)d_in[2];
    const float* bF   = (const float*)d_in[3];
    const float* WihB = (const float*)d_in[4];
    const float* WhhB = (const float*)d_in[5];
    const float* bB   = (const float*)d_in[6];
    float* out = (float*)d_out;
    float* ws = (float*)d_ws;

    k1_xproj<<<160, 256, 0, stream>>>(wr, WihF, bF, WihB, bB, out);
    k2_lstm<<<64, 256, 0, stream>>>(WhhF, WhhB, out, ws);
    k3_out<<<2048, 256, 0, stream>>>(ws, out);
}